// Round 9
// baseline (282.264 us; speedup 1.0000x reference)
//
#include <hip/hip_runtime.h>
#include <hip/hip_bf16.h>

#define HID 128

typedef __attribute__((ext_vector_type(8))) short short8;
typedef __attribute__((ext_vector_type(4))) float f32x4;
typedef __attribute__((ext_vector_type(16))) float f32x16;
typedef __attribute__((ext_vector_type(4))) unsigned int u32x4;

__device__ __forceinline__ short f2bf(float x) {
    __bf16 b = (__bf16)x;
    return __builtin_bit_cast(short, b);
}

// ---------------------------------------------------------------------------
// Prepass 1: pack W1 (256x128 fp32, k-major rows) into 32x32x16 MFMA-B
// fragment order:
//   bpk[((nt*16 + ks)*64 + l)*8 + j]
//     = bf16( W1[(ks*16 + (l>>5)*8 + j)*128 + nt*32 + (l&31)] )
// so each B-fragment is one contiguous 16B ds_read per lane.
// ---------------------------------------------------------------------------
__global__ void pack_w1_kernel(const float* __restrict__ W1, short* __restrict__ bpk) {
    int t = blockIdx.x * 256 + threadIdx.x;   // 0..4095 = nt*1024 + ks*64 + l
    int l  = t & 63;
    int ks = (t >> 6) & 15;
    int nt = t >> 10;
    int k0  = ks * 16 + (l >> 5) * 8;
    int col = nt * 32 + (l & 31);
    short8 v;
#pragma unroll
    for (int j = 0; j < 8; ++j)
        v[j] = f2bf(W1[(k0 + j) * HID + col]);
    *reinterpret_cast<short8*>(&bpk[t * 8]) = v;
}

// ---------------------------------------------------------------------------
// Prepass 2: node-embedding table fp32 -> bf16.
// ---------------------------------------------------------------------------
__global__ __launch_bounds__(256) void conv_emb_kernel(
    const float* __restrict__ emb, short* __restrict__ bemb, int n8) {
    int i = blockIdx.x * 256 + threadIdx.x;
    if (i >= n8) return;
    f32x4 x0 = *reinterpret_cast<const f32x4*>(emb + (size_t)i * 8);
    f32x4 x1 = *reinterpret_cast<const f32x4*>(emb + (size_t)i * 8 + 4);
    short8 v;
#pragma unroll
    for (int j = 0; j < 4; ++j) {
        v[j]     = f2bf(x0[j]);
        v[4 + j] = f2bf(x1[j]);
    }
    *reinterpret_cast<short8*>(&bemb[(size_t)i * 8]) = v;
}

// ---------------------------------------------------------------------------
// Main kernel. Block = 512 threads = 8 waves = 4 edge-groups x 2 N-groups,
// covering 256 edges. Wave tile: 64 edges x 64 cols via mfma_f32_32x32x16_bf16
// (2 M x 2 N x 16 k-steps, acc = 2x2 f32x16 = 64 regs). vs R3 this cuts
// B-LDS bytes/edge 4x (2048->512) and raises MFMA FLOP/cyc ~1.2x. A-fragments
// are double-buffered: k-step ks+1's two gathers issue before ks's MFMAs.
// launch_bounds(512,4): 128-VGPR budget, LDS 64KB -> 2 blocks/CU = 16 waves/CU
// (same occupancy as R3). N-group pairs combine W2-dot partials via LDS.
// MODE: 0 = bf16 table + packed W1, 1 = fp32 gather + packed W1,
//       2 = fp32 gather + in-block W1 pack (no usable ws).
// ---------------------------------------------------------------------------
template <int MODE>
__global__ __launch_bounds__(512, 4) void edge_head_kernel(
    const float* __restrict__ emb,
    const short* __restrict__ bemb,
    const void* __restrict__ src_raw,
    const void* __restrict__ tgt_raw,
    const float* __restrict__ W1,
    const float* __restrict__ b1,
    const float* __restrict__ W2,
    const float* __restrict__ b2,
    const short* __restrict__ bpk,
    float* __restrict__ out,
    int E)
{
    __shared__ short lds_b[32768];   // 64 KB: packed W1 (B-operand)
    __shared__ float lds_part[256];  // N-group partial-sum combine

    const int tid = threadIdx.x;
    const int l   = tid & 63;
    const int wid = tid >> 6;
    const int we  = wid >> 1;        // edge-group (0..3): 64 edges each
    const int wn  = wid & 1;         // N-group (0,1): cols [wn*64, wn*64+64)
    const int lc  = l & 31;          // edge-in-M-tile / C-col-in-N-tile
    const int hi  = l >> 5;          // k-half of A/B frags; row-offset 4*hi in C

    // int64-vs-int32 index detection (JAX may demote int64 -> int32):
    // little-endian int64 (< 2^31) has every odd dword == 0.
    int i64f = 1;
    {
        const int* s32 = (const int*)src_raw;
#pragma unroll
        for (int i = 1; i < 32; i += 2) i64f &= (s32[i] == 0);
    }

    const long long e0 = (long long)blockIdx.x * 256 + we * 64;

    // ---- gathered row offsets for the 2 M-tiles (element offsets: idx*128)
    unsigned so[2], to[2];
#pragma unroll
    for (int m = 0; m < 2; ++m) {
        long long e = e0 + m * 32 + lc;
        if (e >= E) e = E - 1;
        long long si, ti;
        if (i64f) {
            si = ((const long long*)src_raw)[e];
            ti = ((const long long*)tgt_raw)[e];
        } else {
            si = ((const int*)src_raw)[e];
            ti = ((const int*)tgt_raw)[e];
        }
        so[m] = (unsigned)si * HID;
        to[m] = (unsigned)ti * HID;
    }

    // ---- stage packed W1 into LDS
    if (MODE != 2) {
        const u32x4* gsrc = (const u32x4*)bpk;
        u32x4* d = (u32x4*)lds_b;
#pragma unroll
        for (int i = 0; i < 8; ++i) d[i * 512 + tid] = gsrc[i * 512 + tid];
    } else {
        for (int i = 0; i < 64; ++i) {
            int idx = i * 512 + tid;            // 0..32767 over W1
            int k   = idx >> 7;
            int col = idx & 127;
            int nt = col >> 5, lcc = col & 31;
            int ks = k >> 4,  kr = k & 15;
            int h2 = kr >> 3, j = kr & 7;
            int l2 = h2 * 32 + lcc;
            lds_b[(((nt * 16 + ks) * 64 + l2) << 3) + j] = f2bf(W1[idx]);
        }
    }
    __syncthreads();

    f32x16 acc[2][2];
#pragma unroll
    for (int m = 0; m < 2; ++m)
#pragma unroll
        for (int n = 0; n < 2; ++n)
            acc[m][n] = (f32x16)(0.f);

    const unsigned asub = hi * 8;    // lane's k-subgroup within a 16-k step

    // ---- K loop: 16 steps of K=16 (ks<8: src half, ks>=8: tgt half),
    //      A double-buffered one step ahead.
    short8 abuf[2][2];
#pragma unroll
    for (int m = 0; m < 2; ++m) {
        if (MODE == 0) {
            abuf[0][m] = *reinterpret_cast<const short8*>(bemb + so[m] + asub);
        } else {
            const float* p = emb + so[m] + asub;
            f32x4 x0 = *reinterpret_cast<const f32x4*>(p);
            f32x4 x1 = *reinterpret_cast<const f32x4*>(p + 4);
            short8 t;
#pragma unroll
            for (int j = 0; j < 4; ++j) { t[j] = f2bf(x0[j]); t[4 + j] = f2bf(x1[j]); }
            abuf[0][m] = t;
        }
    }

#pragma unroll
    for (int ks = 0; ks < 16; ++ks) {
        const int cur = ks & 1, nxt = cur ^ 1;
        if (ks < 15) {
            const int ks1 = ks + 1;
            const unsigned koff = (unsigned)(ks1 & 7) * 16 + asub;
#pragma unroll
            for (int m = 0; m < 2; ++m) {
                const unsigned off = (ks1 < 8 ? so[m] : to[m]) + koff;
                if (MODE == 0) {
                    abuf[nxt][m] = *reinterpret_cast<const short8*>(bemb + off);
                } else {
                    const float* p = emb + off;
                    f32x4 x0 = *reinterpret_cast<const f32x4*>(p);
                    f32x4 x1 = *reinterpret_cast<const f32x4*>(p + 4);
                    short8 t;
#pragma unroll
                    for (int j = 0; j < 4; ++j) { t[j] = f2bf(x0[j]); t[4 + j] = f2bf(x1[j]); }
                    abuf[nxt][m] = t;
                }
            }
        }
#pragma unroll
        for (int n = 0; n < 2; ++n) {
            const int nt = wn * 2 + n;
            short8 bfr = *reinterpret_cast<const short8*>(&lds_b[((nt * 16 + ks) * 64 + l) * 8]);
#pragma unroll
            for (int m = 0; m < 2; ++m)
                acc[m][n] = __builtin_amdgcn_mfma_f32_32x32x16_bf16(abuf[cur][m], bfr, acc[m][n], 0, 0, 0);
        }
    }

    // ---- epilogue: partial out = sum_{cols in N-group} relu(h+b1)*W2
    // C layout (32x32): col = l&31, row = (r&3) + 8*(r>>2) + 4*hi.
    float b1v[2], w2v[2];
#pragma unroll
    for (int n = 0; n < 2; ++n) {
        const int col = wn * 64 + n * 32 + lc;
        b1v[n] = b1[col];
        w2v[n] = W2[col];
    }
    const float b2s = b2[0];

    float sm[2][16];
#pragma unroll
    for (int m = 0; m < 2; ++m) {
#pragma unroll
        for (int r = 0; r < 16; ++r) {
            float s = fmaxf(acc[m][0][r] + b1v[0], 0.f) * w2v[0]
                    + fmaxf(acc[m][1][r] + b1v[1], 0.f) * w2v[1];
            sm[m][r] = s;
        }
        // reduce across the 32 cols (lanes within each 32-lane half)
#pragma unroll
        for (int w = 1; w < 32; w <<= 1) {
#pragma unroll
            for (int r = 0; r < 16; ++r)
                sm[m][r] += __shfl_xor(sm[m][r], w, 32);
        }
    }

    // ---- combine the two N-group partials via LDS
    if (wn == 0 && lc == 0) {
#pragma unroll
        for (int m = 0; m < 2; ++m)
#pragma unroll
            for (int r = 0; r < 16; ++r) {
                const int row = m * 32 + (r & 3) + 8 * (r >> 2) + 4 * hi;
                lds_part[we * 64 + row] = sm[m][r];
            }
    }
    __syncthreads();
    if (wn == 1 && lc == 0) {
#pragma unroll
        for (int m = 0; m < 2; ++m)
#pragma unroll
            for (int r = 0; r < 16; ++r) {
                const int row = m * 32 + (r & 3) + 8 * (r >> 2) + 4 * hi;
                const long long e = e0 + row;
                if (e < E)
                    out[e] = sm[m][r] + lds_part[we * 64 + row] + b2s;
            }
    }
}

extern "C" void kernel_launch(void* const* d_in, const int* in_sizes, int n_in,
                              void* d_out, int out_size, void* d_ws, size_t ws_size,
                              hipStream_t stream) {
    const float* emb = (const float*)d_in[0];
    const void*  src = d_in[1];
    const void*  tgt = d_in[2];
    // d_in[3] = edge_type_idx (selector; params passed are already the selected ones)
    const float* W1 = (const float*)d_in[4];
    const float* b1 = (const float*)d_in[5];
    const float* W2 = (const float*)d_in[6];
    const float* b2 = (const float*)d_in[7];
    float* out = (float*)d_out;

    const int E = in_sizes[1];
    const int embN = in_sizes[0];             // node_embeddings element count
    const size_t need_full = 65536 + (size_t)embN * sizeof(short);

    short* bpk  = (short*)d_ws;
    short* bemb = (short*)((char*)d_ws + 65536);

    int mode;
    if (ws_size >= need_full)       mode = 0;
    else if (ws_size >= 65536)      mode = 1;
    else                            mode = 2;

    if (mode != 2)
        pack_w1_kernel<<<16, 256, 0, stream>>>(W1, bpk);
    if (mode == 0) {
        const int n8 = embN / 8;
        conv_emb_kernel<<<(n8 + 255) / 256, 256, 0, stream>>>(emb, bemb, n8);
    }

    const int grid = (E + 255) / 256;
    if (mode == 0)
        edge_head_kernel<0><<<grid, 512, 0, stream>>>(emb, bemb, src, tgt, W1, b1, W2, b2, bpk, out, E);
    else if (mode == 1)
        edge_head_kernel<1><<<grid, 512, 0, stream>>>(emb, bemb, src, tgt, W1, b1, W2, b2, bpk, out, E);
    else
        edge_head_kernel<2><<<grid, 512, 0, stream>>>(emb, bemb, src, tgt, W1, b1, W2, b2, bpk, out, E);
}

// Round 10
// 141.932 us; speedup vs baseline: 1.9887x; 1.9887x over previous
//
#include <hip/hip_runtime.h>
#include <hip/hip_bf16.h>

#define HID 128

typedef __attribute__((ext_vector_type(8))) short short8;
typedef __attribute__((ext_vector_type(4))) float f32x4;
typedef __attribute__((ext_vector_type(16))) float f32x16;
typedef __attribute__((ext_vector_type(4))) unsigned int u32x4;

__device__ __forceinline__ short f2bf(float x) {
    __bf16 b = (__bf16)x;
    return __builtin_bit_cast(short, b);
}
__device__ __forceinline__ float bf2f(short s) {
    unsigned u = (unsigned)(unsigned short)s << 16;
    return __builtin_bit_cast(float, u);
}

// ===========================================================================
// NEW FACTORED PATH: U = emb@W1[:128], V = emb@W1[128:] (dense, per-node),
// then out[e] = relu(U[src]+V[tgt]+b1)@W2 + b2 (pure gather+VALU, no MFMA).
// ===========================================================================

// ---------------------------------------------------------------------------
// Pack W1 halves into 32x32x16 MFMA-B fragment order, both halves:
// bpk2[(((half*4+nt)*8+ks)*64+l)*8+j]
//   = bf16( W1[(half*128 + ks*16 + (l>>5)*8 + j)*128 + nt*32 + (l&31)] )
// ---------------------------------------------------------------------------
__global__ void pack_w1_uv_kernel(const float* __restrict__ W1, short* __restrict__ bpk2) {
    int t = blockIdx.x * 256 + threadIdx.x;   // 0..4095 = half*2048 + nt*512 + ks*64 + l
    int l    = t & 63;
    int ks   = (t >> 6) & 7;
    int nt   = (t >> 9) & 3;
    int half = t >> 11;
    int k0  = half * 128 + ks * 16 + (l >> 5) * 8;
    int col = nt * 32 + (l & 31);
    short8 v;
#pragma unroll
    for (int j = 0; j < 8; ++j)
        v[j] = f2bf(W1[(k0 + j) * HID + col]);
    *reinterpret_cast<short8*>(&bpk2[t * 8]) = v;
}

// ---------------------------------------------------------------------------
// UV precompute: U[n][c] = bf16( sum_k bf16(emb[n][k]) * bf16(W1a[k][c]) ),
// same for V with W1b. Block = 512 thr = 8 waves = 4 node-groups x 2 col-
// groups = 128 nodes/block. mfma_f32_32x32x16_bf16, acc = 2(U/V)x2(n)x16.
// ---------------------------------------------------------------------------
__global__ __launch_bounds__(512, 4) void uv_kernel(
    const float* __restrict__ emb,
    const short* __restrict__ bpk2,
    short* __restrict__ U,
    short* __restrict__ V,
    int Nn)
{
    __shared__ short lds_b[32768];   // 64 KB packed W1 (both halves)

    const int tid = threadIdx.x;
    const int l   = tid & 63;
    const int wid = tid >> 6;
    const int wg  = wid >> 1;        // node-group 0..3
    const int wn  = wid & 1;         // col-group 0..1
    const int lc  = l & 31;
    const int hi  = l >> 5;

    {
        const u32x4* g = (const u32x4*)bpk2;
        u32x4* d = (u32x4*)lds_b;
#pragma unroll
        for (int i = 0; i < 8; ++i) d[i * 512 + tid] = g[i * 512 + tid];
    }
    __syncthreads();

    const int base = blockIdx.x * 128 + wg * 32;
    int nr = base + lc;
    if (nr >= Nn) nr = Nn - 1;

    f32x16 accU[2], accV[2];
#pragma unroll
    for (int n = 0; n < 2; ++n) { accU[n] = (f32x16)(0.f); accV[n] = (f32x16)(0.f); }

#pragma unroll
    for (int ks = 0; ks < 8; ++ks) {
        const float* p = emb + (size_t)nr * HID + ks * 16 + hi * 8;
        f32x4 x0 = *reinterpret_cast<const f32x4*>(p);
        f32x4 x1 = *reinterpret_cast<const f32x4*>(p + 4);
        short8 afr;
#pragma unroll
        for (int j = 0; j < 4; ++j) { afr[j] = f2bf(x0[j]); afr[4 + j] = f2bf(x1[j]); }
#pragma unroll
        for (int n = 0; n < 2; ++n) {
            const int nt = wn * 2 + n;
            short8 bU = *reinterpret_cast<const short8*>(&lds_b[(((0 + nt) * 8 + ks) * 64 + l) * 8]);
            short8 bV = *reinterpret_cast<const short8*>(&lds_b[(((4 + nt) * 8 + ks) * 64 + l) * 8]);
            accU[n] = __builtin_amdgcn_mfma_f32_32x32x16_bf16(afr, bU, accU[n], 0, 0, 0);
            accV[n] = __builtin_amdgcn_mfma_f32_32x32x16_bf16(afr, bV, accV[n], 0, 0, 0);
        }
    }

    // C layout (32x32): col = l&31, row = (r&3) + 8*(r>>2) + 4*hi
#pragma unroll
    for (int n = 0; n < 2; ++n) {
        const int col = wn * 64 + n * 32 + lc;
#pragma unroll
        for (int r = 0; r < 16; ++r) {
            const int row = (r & 3) + 8 * (r >> 2) + 4 * hi;
            const int node = base + row;
            if (node < Nn) {
                U[(size_t)node * HID + col] = f2bf(accU[n][r]);
                V[(size_t)node * HID + col] = f2bf(accV[n][r]);
            }
        }
    }
}

// ---------------------------------------------------------------------------
// Edge pass: out[e] = relu(U[src]+V[tgt]+b1)@W2 + b2. 16 lanes/edge, 8 cols/
// lane, 16 edges/wave (4 groups, loads all issued up front), 4 waves/block.
// ~70 VGPR -> ~28 waves/CU: gather latency hidden by TLP+MLP.
// ---------------------------------------------------------------------------
__global__ __launch_bounds__(256) void edge_pass_kernel(
    const short* __restrict__ U,
    const short* __restrict__ V,
    const void* __restrict__ src_raw,
    const void* __restrict__ tgt_raw,
    const float* __restrict__ b1,
    const float* __restrict__ W2,
    const float* __restrict__ b2,
    float* __restrict__ out,
    int E)
{
    const int tid = threadIdx.x;
    const int l   = tid & 63;
    const int wid = tid >> 6;
    const int le  = l >> 4;          // edge slot in group (0..3)
    const int lc  = l & 15;          // col group: cols [lc*8, lc*8+8)

    // int64-vs-int32 index detection (JAX may demote int64 -> int32).
    int i64f = 1;
    {
        const int* s32 = (const int*)src_raw;
#pragma unroll
        for (int i = 1; i < 32; i += 2) i64f &= (s32[i] == 0);
    }

    float b1v[8], w2v[8];
    {
        f32x4 a = *reinterpret_cast<const f32x4*>(b1 + lc * 8);
        f32x4 b = *reinterpret_cast<const f32x4*>(b1 + lc * 8 + 4);
        f32x4 c = *reinterpret_cast<const f32x4*>(W2 + lc * 8);
        f32x4 d = *reinterpret_cast<const f32x4*>(W2 + lc * 8 + 4);
#pragma unroll
        for (int j = 0; j < 4; ++j) {
            b1v[j] = a[j]; b1v[4 + j] = b[j];
            w2v[j] = c[j]; w2v[4 + j] = d[j];
        }
    }
    const float b2s = b2[0];

    const long long ebase = ((long long)blockIdx.x * 4 + wid) * 16;

    short8 ub[4], vb[4];
#pragma unroll
    for (int g = 0; g < 4; ++g) {
        long long e = ebase + g * 4 + le;
        if (e >= E) e = E - 1;
        long long si, ti;
        if (i64f) {
            si = ((const long long*)src_raw)[e];
            ti = ((const long long*)tgt_raw)[e];
        } else {
            si = ((const int*)src_raw)[e];
            ti = ((const int*)tgt_raw)[e];
        }
        ub[g] = *reinterpret_cast<const short8*>(U + (unsigned)si * HID + lc * 8);
        vb[g] = *reinterpret_cast<const short8*>(V + (unsigned)ti * HID + lc * 8);
    }

#pragma unroll
    for (int g = 0; g < 4; ++g) {
        float s = 0.f;
#pragma unroll
        for (int j = 0; j < 8; ++j) {
            float h = bf2f(ub[g][j]) + bf2f(vb[g][j]) + b1v[j];
            s += fmaxf(h, 0.f) * w2v[j];
        }
#pragma unroll
        for (int w = 1; w < 16; w <<= 1)
            s += __shfl_xor(s, w, 16);
        const long long e = ebase + g * 4 + le;
        if (lc == 0 && e < E)
            out[e] = s + b2s;
    }
}

// ===========================================================================
// FALLBACK PATH (R3, proven 160us): MFMA over gathered rows.
// ===========================================================================

__global__ void pack_w1_kernel(const float* __restrict__ W1, short* __restrict__ bpk) {
    int t = blockIdx.x * 256 + threadIdx.x;   // 0..4095 = n*512 + f*64 + l
    int f = (t >> 6) & 7;
    int l = t & 63;
    int n = t >> 9;
    int c = l & 15, kb = l >> 4;
    int k0 = f * 32 + kb * 8;
    short8 v;
#pragma unroll
    for (int j = 0; j < 8; ++j)
        v[j] = f2bf(W1[(k0 + j) * HID + n * 16 + c]);
    *reinterpret_cast<short8*>(&bpk[t * 8]) = v;
}

__global__ __launch_bounds__(256) void conv_emb_kernel(
    const float* __restrict__ emb, short* __restrict__ bemb, int n8) {
    int i = blockIdx.x * 256 + threadIdx.x;
    if (i >= n8) return;
    f32x4 x0 = *reinterpret_cast<const f32x4*>(emb + (size_t)i * 8);
    f32x4 x1 = *reinterpret_cast<const f32x4*>(emb + (size_t)i * 8 + 4);
    short8 v;
#pragma unroll
    for (int j = 0; j < 4; ++j) {
        v[j]     = f2bf(x0[j]);
        v[4 + j] = f2bf(x1[j]);
    }
    *reinterpret_cast<short8*>(&bemb[(size_t)i * 8]) = v;
}

template <int MODE>
__global__ __launch_bounds__(512, 4) void edge_head_kernel(
    const float* __restrict__ emb,
    const short* __restrict__ bemb,
    const void* __restrict__ src_raw,
    const void* __restrict__ tgt_raw,
    const float* __restrict__ W1,
    const float* __restrict__ b1,
    const float* __restrict__ W2,
    const float* __restrict__ b2,
    const short* __restrict__ bpk,
    float* __restrict__ out,
    int E)
{
    __shared__ short lds_b[32768];

    const int tid = threadIdx.x;

    int i64f = 1;
    {
        const int* s32 = (const int*)src_raw;
#pragma unroll
        for (int i = 1; i < 32; i += 2) i64f &= (s32[i] == 0);
    }

    if (MODE != 2) {
        const u32x4* g = (const u32x4*)bpk;
        u32x4* d = (u32x4*)lds_b;
#pragma unroll
        for (int i = 0; i < 8; ++i) d[i * 512 + tid] = g[i * 512 + tid];
    } else {
        for (int i = 0; i < 64; ++i) {
            int idx = i * 512 + tid;
            int col = idx & 127;
            int k   = idx >> 7;
            int n = col >> 4, cc = col & 15;
            int f = k >> 5, kb = (k >> 3) & 3, j = k & 7;
            int l2 = kb * 16 + cc;
            lds_b[(((n * 8 + f) * 64 + l2) << 3) + j] = f2bf(W1[idx]);
        }
    }
    __syncthreads();

    const int l = tid & 63;
    const int wid = tid >> 6;
    const int c = l & 15;
    const int g = l >> 4;
    const long long e0 = (long long)blockIdx.x * 256 + wid * 32;

    unsigned so[2], to[2];
#pragma unroll
    for (int m = 0; m < 2; ++m) {
        long long e = e0 + m * 16 + c;
        if (e >= E) e = E - 1;
        long long si, ti;
        if (i64f) {
            si = ((const long long*)src_raw)[e];
            ti = ((const long long*)tgt_raw)[e];
        } else {
            si = ((const int*)src_raw)[e];
            ti = ((const int*)tgt_raw)[e];
        }
        so[m] = (unsigned)si * HID;
        to[m] = (unsigned)ti * HID;
    }

    f32x4 acc[2][8];
#pragma unroll
    for (int m = 0; m < 2; ++m)
#pragma unroll
        for (int n = 0; n < 8; ++n)
            acc[m][n] = (f32x4){0.f, 0.f, 0.f, 0.f};

    const int koff = g * 8;
#pragma unroll
    for (int f = 0; f < 8; ++f) {
        short8 afr[2];
        const int k0 = (f & 3) * 32 + koff;
#pragma unroll
        for (int m = 0; m < 2; ++m) {
            const unsigned off = (f < 4 ? so[m] : to[m]) + k0;
            if (MODE == 0) {
                afr[m] = *reinterpret_cast<const short8*>(bemb + off);
            } else {
                f32x4 x0 = *reinterpret_cast<const f32x4*>(emb + off);
                f32x4 x1 = *reinterpret_cast<const f32x4*>(emb + off + 4);
                short8 t;
#pragma unroll
                for (int j = 0; j < 4; ++j) {
                    t[j]     = f2bf(x0[j]);
                    t[4 + j] = f2bf(x1[j]);
                }
                afr[m] = t;
            }
        }
#pragma unroll
        for (int n = 0; n < 8; ++n) {
            short8 bfr = *reinterpret_cast<const short8*>(&lds_b[((n * 8 + f) * 64 + l) * 8]);
#pragma unroll
            for (int m = 0; m < 2; ++m)
                acc[m][n] = __builtin_amdgcn_mfma_f32_16x16x32_bf16(afr[m], bfr, acc[m][n], 0, 0, 0);
        }
    }

    float b1v[8], w2v[8];
#pragma unroll
    for (int n = 0; n < 8; ++n) {
        b1v[n] = b1[n * 16 + c];
        w2v[n] = W2[n * 16 + c];
    }
    const float b2s = b2[0];

#pragma unroll
    for (int m = 0; m < 2; ++m) {
        float s[4] = {0.f, 0.f, 0.f, 0.f};
#pragma unroll
        for (int n = 0; n < 8; ++n) {
#pragma unroll
            for (int r = 0; r < 4; ++r)
                s[r] += fmaxf(acc[m][n][r] + b1v[n], 0.f) * w2v[n];
        }
#pragma unroll
        for (int w = 1; w < 16; w <<= 1) {
#pragma unroll
            for (int r = 0; r < 4; ++r)
                s[r] += __shfl_xor(s[r], w, 16);
        }
        if (c == 0) {
            const long long eb = e0 + m * 16 + g * 4;
#pragma unroll
            for (int r = 0; r < 4; ++r)
                if (eb + r < E) out[eb + r] = s[r] + b2s;
        }
    }
}

extern "C" void kernel_launch(void* const* d_in, const int* in_sizes, int n_in,
                              void* d_out, int out_size, void* d_ws, size_t ws_size,
                              hipStream_t stream) {
    const float* emb = (const float*)d_in[0];
    const void*  src = d_in[1];
    const void*  tgt = d_in[2];
    // d_in[3] = edge_type_idx (selector; params passed are already the selected ones)
    const float* W1 = (const float*)d_in[4];
    const float* b1 = (const float*)d_in[5];
    const float* W2 = (const float*)d_in[6];
    const float* b2 = (const float*)d_in[7];
    float* out = (float*)d_out;

    const int E  = in_sizes[1];
    const int Nn = in_sizes[0] / HID;          // node count

    const size_t uv_bytes   = (size_t)Nn * HID * sizeof(short);
    const size_t need_uv    = 65536 + 2 * uv_bytes;
    const size_t need_old   = 65536 + (size_t)in_sizes[0] * sizeof(short);

    if (ws_size >= need_uv) {
        // ---- factored path: pack W1 -> UV precompute -> edge pass
        short* bpk2 = (short*)d_ws;
        short* U    = (short*)((char*)d_ws + 65536);
        short* Vv   = (short*)((char*)d_ws + 65536 + uv_bytes);

        pack_w1_uv_kernel<<<16, 256, 0, stream>>>(W1, bpk2);
        uv_kernel<<<(Nn + 127) / 128, 512, 0, stream>>>(emb, bpk2, U, Vv, Nn);
        edge_pass_kernel<<<(E + 63) / 64, 256, 0, stream>>>(U, Vv, src, tgt, b1, W2, b2, out, E);
        return;
    }

    // ---- fallback: R3 gathered-MFMA path
    short* bpk  = (short*)d_ws;
    short* bemb = (short*)((char*)d_ws + 65536);

    int mode;
    if (ws_size >= need_old)        mode = 0;
    else if (ws_size >= 65536)      mode = 1;
    else                            mode = 2;

    if (mode != 2)
        pack_w1_kernel<<<16, 256, 0, stream>>>(W1, bpk);
    if (mode == 0) {
        const int n8 = in_sizes[0] / 8;
        conv_emb_kernel<<<(n8 + 255) / 256, 256, 0, stream>>>(emb, bemb, n8);
    }

    const int grid = (E + 255) / 256;
    if (mode == 0)
        edge_head_kernel<0><<<grid, 512, 0, stream>>>(emb, bemb, src, tgt, W1, b1, W2, b2, bpk, out, E);
    else if (mode == 1)
        edge_head_kernel<1><<<grid, 512, 0, stream>>>(emb, bemb, src, tgt, W1, b1, W2, b2, bpk, out, E);
    else
        edge_head_kernel<2><<<grid, 512, 0, stream>>>(emb, bemb, src, tgt, W1, b1, W2, b2, bpk, out, E);
}

// Round 12
// 141.214 us; speedup vs baseline: 1.9988x; 1.0051x over previous
//
#include <hip/hip_runtime.h>
#include <hip/hip_bf16.h>

#define HID 128

typedef __attribute__((ext_vector_type(8))) short short8;
typedef __attribute__((ext_vector_type(4))) float f32x4;
typedef __attribute__((ext_vector_type(16))) float f32x16;
typedef __attribute__((ext_vector_type(4))) unsigned int u32x4;
typedef __attribute__((ext_vector_type(2))) _Float16 h2;

__device__ __forceinline__ short f2bf(float x) {
    __bf16 b = (__bf16)x;
    return __builtin_bit_cast(short, b);
}
__device__ __forceinline__ float bf2f(short s) {
    unsigned u = (unsigned)(unsigned short)s << 16;
    return __builtin_bit_cast(float, u);
}

// ===========================================================================
// FACTORED PATH: U = emb@W1[:128], V = emb@W1[128:] (dense per-node GEMM),
// then out[e] = relu(U[src]+V[tgt]+b1)@W2 + b2 (gather + packed-fp16 VALU).
// U/V stored as fp16 (same bytes as bf16, more mantissa, enables v_pk_* ops).
// ===========================================================================

// ---------------------------------------------------------------------------
// Pack W1 halves into 32x32x16 MFMA-B fragment order (bf16), both halves:
// bpk2[(((half*4+nt)*8+ks)*64+l)*8+j]
//   = bf16( W1[(half*128 + ks*16 + (l>>5)*8 + j)*128 + nt*32 + (l&31)] )
// ---------------------------------------------------------------------------
__global__ void pack_w1_uv_kernel(const float* __restrict__ W1, short* __restrict__ bpk2) {
    int t = blockIdx.x * 256 + threadIdx.x;   // 0..4095 = half*2048 + nt*512 + ks*64 + l
    int l    = t & 63;
    int ks   = (t >> 6) & 7;
    int nt   = (t >> 9) & 3;
    int half = t >> 11;
    int k0  = half * 128 + ks * 16 + (l >> 5) * 8;
    int col = nt * 32 + (l & 31);
    short8 v;
#pragma unroll
    for (int j = 0; j < 8; ++j)
        v[j] = f2bf(W1[(k0 + j) * HID + col]);
    *reinterpret_cast<short8*>(&bpk2[t * 8]) = v;
}

// ---------------------------------------------------------------------------
// UV precompute: U[n][c] = fp16( sum_k bf16(emb[n][k]) * bf16(W1a[k][c]) ),
// same for V with W1b. Block = 512 thr = 8 waves = 4 node-groups x 2 col-
// groups = 128 nodes/block. mfma_f32_32x32x16_bf16, acc = 2(U/V)x2(n)x16.
// ---------------------------------------------------------------------------
__global__ __launch_bounds__(512, 4) void uv_kernel(
    const float* __restrict__ emb,
    const short* __restrict__ bpk2,
    unsigned short* __restrict__ U,
    unsigned short* __restrict__ V,
    int Nn)
{
    __shared__ short lds_b[32768];   // 64 KB packed W1 (both halves)

    const int tid = threadIdx.x;
    const int l   = tid & 63;
    const int wid = tid >> 6;
    const int wg  = wid >> 1;        // node-group 0..3
    const int wn  = wid & 1;         // col-group 0..1
    const int lc  = l & 31;
    const int hi  = l >> 5;

    {
        const u32x4* g = (const u32x4*)bpk2;
        u32x4* d = (u32x4*)lds_b;
#pragma unroll
        for (int i = 0; i < 8; ++i) d[i * 512 + tid] = g[i * 512 + tid];
    }
    __syncthreads();

    const int base = blockIdx.x * 128 + wg * 32;
    int nr = base + lc;
    if (nr >= Nn) nr = Nn - 1;

    f32x16 accU[2], accV[2];
#pragma unroll
    for (int n = 0; n < 2; ++n) { accU[n] = (f32x16)(0.f); accV[n] = (f32x16)(0.f); }

#pragma unroll
    for (int ks = 0; ks < 8; ++ks) {
        const float* p = emb + (size_t)nr * HID + ks * 16 + hi * 8;
        f32x4 x0 = *reinterpret_cast<const f32x4*>(p);
        f32x4 x1 = *reinterpret_cast<const f32x4*>(p + 4);
        short8 afr;
#pragma unroll
        for (int j = 0; j < 4; ++j) { afr[j] = f2bf(x0[j]); afr[4 + j] = f2bf(x1[j]); }
#pragma unroll
        for (int n = 0; n < 2; ++n) {
            const int nt = wn * 2 + n;
            short8 bU = *reinterpret_cast<const short8*>(&lds_b[(((0 + nt) * 8 + ks) * 64 + l) * 8]);
            short8 bV = *reinterpret_cast<const short8*>(&lds_b[(((4 + nt) * 8 + ks) * 64 + l) * 8]);
            accU[n] = __builtin_amdgcn_mfma_f32_32x32x16_bf16(afr, bU, accU[n], 0, 0, 0);
            accV[n] = __builtin_amdgcn_mfma_f32_32x32x16_bf16(afr, bV, accV[n], 0, 0, 0);
        }
    }

    // C layout (32x32): col = l&31, row = (r&3) + 8*(r>>2) + 4*hi
#pragma unroll
    for (int n = 0; n < 2; ++n) {
        const int col = wn * 64 + n * 32 + lc;
#pragma unroll
        for (int r = 0; r < 16; ++r) {
            const int row = (r & 3) + 8 * (r >> 2) + 4 * hi;
            const int node = base + row;
            if (node < Nn) {
                _Float16 hu = (_Float16)accU[n][r];
                _Float16 hv = (_Float16)accV[n][r];
                U[(size_t)node * HID + col] = __builtin_bit_cast(unsigned short, hu);
                V[(size_t)node * HID + col] = __builtin_bit_cast(unsigned short, hv);
            }
        }
    }
}

// ---------------------------------------------------------------------------
// Edge pass: out[e] = relu(U[src]+V[tgt]+b1)@W2 + b2 in packed fp16 (clang
// ext_vector _Float16: +,* -> v_pk_add/fma_f16, __builtin_elementwise_max ->
// v_pk_max_f16). 16 lanes/edge (8 cols each), 16 edges/wave, all 8 gathers
// issued up front. fp16 accumulates only 4 terms/lane before fp32 reduce.
// ---------------------------------------------------------------------------
__global__ __launch_bounds__(256) void edge_pass_kernel(
    const unsigned short* __restrict__ U,
    const unsigned short* __restrict__ V,
    const void* __restrict__ src_raw,
    const void* __restrict__ tgt_raw,
    const float* __restrict__ b1,
    const float* __restrict__ W2,
    const float* __restrict__ b2,
    float* __restrict__ out,
    int E)
{
    const int tid = threadIdx.x;
    const int l   = tid & 63;
    const int wid = tid >> 6;
    const int le  = l >> 4;          // edge slot in group (0..3)
    const int lc  = l & 15;          // col group: cols [lc*8, lc*8+8)

    // wave-parallel int64-vs-int32 index probe: int64 (<2^31) => all odd
    // dwords of the first 32 entries are zero.
    int oddw = 0;
    {
        const int* s32 = (const int*)src_raw;
        if (l < 32) oddw = s32[2 * l + 1];
    }
    const bool i64f = (__ballot(oddw != 0) == 0ULL);

    h2 b1p[4], w2p[4];
    {
        f32x4 a = *reinterpret_cast<const f32x4*>(b1 + lc * 8);
        f32x4 b = *reinterpret_cast<const f32x4*>(b1 + lc * 8 + 4);
        f32x4 c = *reinterpret_cast<const f32x4*>(W2 + lc * 8);
        f32x4 d = *reinterpret_cast<const f32x4*>(W2 + lc * 8 + 4);
#pragma unroll
        for (int j = 0; j < 2; ++j) {
            b1p[0][j] = (_Float16)a[j];     b1p[1][j] = (_Float16)a[2 + j];
            b1p[2][j] = (_Float16)b[j];     b1p[3][j] = (_Float16)b[2 + j];
            w2p[0][j] = (_Float16)c[j];     w2p[1][j] = (_Float16)c[2 + j];
            w2p[2][j] = (_Float16)d[j];     w2p[3][j] = (_Float16)d[2 + j];
        }
    }
    const float b2s = b2[0];
    const h2 zero2 = (h2)((_Float16)0.f);

    const long long ebase = ((long long)blockIdx.x * 4 + wid) * 16;

    short8 ub[4], vb[4];
#pragma unroll
    for (int g = 0; g < 4; ++g) {
        long long e = ebase + g * 4 + le;
        if (e >= E) e = E - 1;
        long long si, ti;
        if (i64f) {
            si = ((const long long*)src_raw)[e];
            ti = ((const long long*)tgt_raw)[e];
        } else {
            si = ((const int*)src_raw)[e];
            ti = ((const int*)tgt_raw)[e];
        }
        ub[g] = *reinterpret_cast<const short8*>(U + (unsigned)si * HID + lc * 8);
        vb[g] = *reinterpret_cast<const short8*>(V + (unsigned)ti * HID + lc * 8);
    }

#pragma unroll
    for (int g = 0; g < 4; ++g) {
        const unsigned int* uw = (const unsigned int*)&ub[g];
        const unsigned int* vw = (const unsigned int*)&vb[g];
        h2 s2 = zero2;
#pragma unroll
        for (int j = 0; j < 4; ++j) {
            h2 hu = __builtin_bit_cast(h2, uw[j]);
            h2 hv = __builtin_bit_cast(h2, vw[j]);
            h2 h  = hu + hv + b1p[j];
            h = __builtin_elementwise_max(h, zero2);
            s2 = s2 + h * w2p[j];
        }
        float s = (float)s2[0] + (float)s2[1];
#pragma unroll
        for (int w = 1; w < 16; w <<= 1)
            s += __shfl_xor(s, w, 16);
        const long long e = ebase + g * 4 + le;
        if (lc == 0 && e < E)
            out[e] = s + b2s;
    }
}

// ===========================================================================
// FALLBACK PATH (R3, proven 160us): MFMA over gathered rows (bf16).
// ===========================================================================

__global__ void pack_w1_kernel(const float* __restrict__ W1, short* __restrict__ bpk) {
    int t = blockIdx.x * 256 + threadIdx.x;   // 0..4095 = n*512 + f*64 + l
    int f = (t >> 6) & 7;
    int l = t & 63;
    int n = t >> 9;
    int c = l & 15, kb = l >> 4;
    int k0 = f * 32 + kb * 8;
    short8 v;
#pragma unroll
    for (int j = 0; j < 8; ++j)
        v[j] = f2bf(W1[(k0 + j) * HID + n * 16 + c]);
    *reinterpret_cast<short8*>(&bpk[t * 8]) = v;
}

__global__ __launch_bounds__(256) void conv_emb_kernel(
    const float* __restrict__ emb, short* __restrict__ bemb, int n8) {
    int i = blockIdx.x * 256 + threadIdx.x;
    if (i >= n8) return;
    f32x4 x0 = *reinterpret_cast<const f32x4*>(emb + (size_t)i * 8);
    f32x4 x1 = *reinterpret_cast<const f32x4*>(emb + (size_t)i * 8 + 4);
    short8 v;
#pragma unroll
    for (int j = 0; j < 4; ++j) {
        v[j]     = f2bf(x0[j]);
        v[4 + j] = f2bf(x1[j]);
    }
    *reinterpret_cast<short8*>(&bemb[(size_t)i * 8]) = v;
}

template <int MODE>
__global__ __launch_bounds__(512, 4) void edge_head_kernel(
    const float* __restrict__ emb,
    const short* __restrict__ bemb,
    const void* __restrict__ src_raw,
    const void* __restrict__ tgt_raw,
    const float* __restrict__ W1,
    const float* __restrict__ b1,
    const float* __restrict__ W2,
    const float* __restrict__ b2,
    const short* __restrict__ bpk,
    float* __restrict__ out,
    int E)
{
    __shared__ short lds_b[32768];

    const int tid = threadIdx.x;

    int i64f = 1;
    {
        const int* s32 = (const int*)src_raw;
#pragma unroll
        for (int i = 1; i < 32; i += 2) i64f &= (s32[i] == 0);
    }

    if (MODE != 2) {
        const u32x4* g = (const u32x4*)bpk;
        u32x4* d = (u32x4*)lds_b;
#pragma unroll
        for (int i = 0; i < 8; ++i) d[i * 512 + tid] = g[i * 512 + tid];
    } else {
        for (int i = 0; i < 64; ++i) {
            int idx = i * 512 + tid;
            int col = idx & 127;
            int k   = idx >> 7;
            int n = col >> 4, cc = col & 15;
            int f = k >> 5, kb = (k >> 3) & 3, j = k & 7;
            int l2 = kb * 16 + cc;
            lds_b[(((n * 8 + f) * 64 + l2) << 3) + j] = f2bf(W1[idx]);
        }
    }
    __syncthreads();

    const int l = tid & 63;
    const int wid = tid >> 6;
    const int c = l & 15;
    const int g = l >> 4;
    const long long e0 = (long long)blockIdx.x * 256 + wid * 32;

    unsigned so[2], to[2];
#pragma unroll
    for (int m = 0; m < 2; ++m) {
        long long e = e0 + m * 16 + c;
        if (e >= E) e = E - 1;
        long long si, ti;
        if (i64f) {
            si = ((const long long*)src_raw)[e];
            ti = ((const long long*)tgt_raw)[e];
        } else {
            si = ((const int*)src_raw)[e];
            ti = ((const int*)tgt_raw)[e];
        }
        so[m] = (unsigned)si * HID;
        to[m] = (unsigned)ti * HID;
    }

    f32x4 acc[2][8];
#pragma unroll
    for (int m = 0; m < 2; ++m)
#pragma unroll
        for (int n = 0; n < 8; ++n)
            acc[m][n] = (f32x4){0.f, 0.f, 0.f, 0.f};

    const int koff = g * 8;
#pragma unroll
    for (int f = 0; f < 8; ++f) {
        short8 afr[2];
        const int k0 = (f & 3) * 32 + koff;
#pragma unroll
        for (int m = 0; m < 2; ++m) {
            const unsigned off = (f < 4 ? so[m] : to[m]) + k0;
            if (MODE == 0) {
                afr[m] = *reinterpret_cast<const short8*>(bemb + off);
            } else {
                f32x4 x0 = *reinterpret_cast<const f32x4*>(emb + off);
                f32x4 x1 = *reinterpret_cast<const f32x4*>(emb + off + 4);
                short8 t;
#pragma unroll
                for (int j = 0; j < 4; ++j) {
                    t[j]     = f2bf(x0[j]);
                    t[4 + j] = f2bf(x1[j]);
                }
                afr[m] = t;
            }
        }
#pragma unroll
        for (int n = 0; n < 8; ++n) {
            short8 bfr = *reinterpret_cast<const short8*>(&lds_b[((n * 8 + f) * 64 + l) * 8]);
#pragma unroll
            for (int m = 0; m < 2; ++m)
                acc[m][n] = __builtin_amdgcn_mfma_f32_16x16x32_bf16(afr[m], bfr, acc[m][n], 0, 0, 0);
        }
    }

    float b1v[8], w2v[8];
#pragma unroll
    for (int n = 0; n < 8; ++n) {
        b1v[n] = b1[n * 16 + c];
        w2v[n] = W2[n * 16 + c];
    }
    const float b2s = b2[0];

#pragma unroll
    for (int m = 0; m < 2; ++m) {
        float s[4] = {0.f, 0.f, 0.f, 0.f};
#pragma unroll
        for (int n = 0; n < 8; ++n) {
#pragma unroll
            for (int r = 0; r < 4; ++r)
                s[r] += fmaxf(acc[m][n][r] + b1v[n], 0.f) * w2v[n];
        }
#pragma unroll
        for (int w = 1; w < 16; w <<= 1) {
#pragma unroll
            for (int r = 0; r < 4; ++r)
                s[r] += __shfl_xor(s[r], w, 16);
        }
        if (c == 0) {
            const long long eb = e0 + m * 16 + g * 4;
#pragma unroll
            for (int r = 0; r < 4; ++r)
                if (eb + r < E) out[eb + r] = s[r] + b2s;
        }
    }
}

extern "C" void kernel_launch(void* const* d_in, const int* in_sizes, int n_in,
                              void* d_out, int out_size, void* d_ws, size_t ws_size,
                              hipStream_t stream) {
    const float* emb = (const float*)d_in[0];
    const void*  src = d_in[1];
    const void*  tgt = d_in[2];
    // d_in[3] = edge_type_idx (selector; params passed are already the selected ones)
    const float* W1 = (const float*)d_in[4];
    const float* b1 = (const float*)d_in[5];
    const float* W2 = (const float*)d_in[6];
    const float* b2 = (const float*)d_in[7];
    float* out = (float*)d_out;

    const int E  = in_sizes[1];
    const int Nn = in_sizes[0] / HID;          // node count

    const size_t uv_bytes   = (size_t)Nn * HID * sizeof(short);
    const size_t need_uv    = 65536 + 2 * uv_bytes;
    const size_t need_old   = 65536 + (size_t)in_sizes[0] * sizeof(short);

    if (ws_size >= need_uv) {
        // ---- factored path: pack W1 -> UV precompute -> edge pass
        short*          bpk2 = (short*)d_ws;
        unsigned short* U    = (unsigned short*)((char*)d_ws + 65536);
        unsigned short* Vv   = (unsigned short*)((char*)d_ws + 65536 + uv_bytes);

        pack_w1_uv_kernel<<<16, 256, 0, stream>>>(W1, bpk2);
        uv_kernel<<<(Nn + 127) / 128, 512, 0, stream>>>(emb, bpk2, U, Vv, Nn);
        edge_pass_kernel<<<(E + 63) / 64, 256, 0, stream>>>(U, Vv, src, tgt, b1, W2, b2, out, E);
        return;
    }

    // ---- fallback: R3 gathered-MFMA path
    short* bpk  = (short*)d_ws;
    short* bemb = (short*)((char*)d_ws + 65536);

    int mode;
    if (ws_size >= need_old)        mode = 0;
    else if (ws_size >= 65536)      mode = 1;
    else                            mode = 2;

    if (mode != 2)
        pack_w1_kernel<<<16, 256, 0, stream>>>(W1, bpk);
    if (mode == 0) {
        const int n8 = in_sizes[0] / 8;
        conv_emb_kernel<<<(n8 + 255) / 256, 256, 0, stream>>>(emb, bemb, n8);
    }

    const int grid = (E + 255) / 256;
    if (mode == 0)
        edge_head_kernel<0><<<grid, 512, 0, stream>>>(emb, bemb, src, tgt, W1, b1, W2, b2, bpk, out, E);
    else if (mode == 1)
        edge_head_kernel<1><<<grid, 512, 0, stream>>>(emb, bemb, src, tgt, W1, b1, W2, b2, bpk, out, E);
    else
        edge_head_kernel<2><<<grid, 512, 0, stream>>>(emb, bemb, src, tgt, W1, b1, W2, b2, bpk, out, E);
}